// Round 3
// baseline (1396.512 us; speedup 1.0000x reference)
//
#include <hip/hip_runtime.h>

#define N_NODES 100000
#define N_EDGES 3200000
#define NFEAT 512
#define NHID 256
#define NCLASS 64
#define FCAT 128   // 2*NCLASS
#define NB 782     // ceil(N_NODES / 128) buckets of 128 rows

typedef __attribute__((ext_vector_type(8))) short short8;
typedef __attribute__((ext_vector_type(4))) float f32x4;

static __device__ __forceinline__ unsigned short f2bf(float f) {
    unsigned u = __float_as_uint(f);
    unsigned r = (u + 0x7FFF + ((u >> 16) & 1)) >> 16;  // RNE
    return (unsigned short)r;
}
static __device__ __forceinline__ float bf2f(unsigned s) {
    return __uint_as_float(s << 16);
}

// ---------------------------------------------------------------------------
// Weight prep: WT[j][k] = Wcat[k][j] = sum_m W1[k][m] * (j<64 ? W2 : Wres)[m][j&63]
// stored bf16, N-major [FCAT][NFEAT] so MFMA B-fragments are k-contiguous.
// ---------------------------------------------------------------------------
__global__ void k_prep_wcat(const float* __restrict__ W1, const float* __restrict__ W2,
                            const float* __restrict__ Wres, unsigned short* __restrict__ WT) {
    int k = blockIdx.x;        // 0..511
    int j = threadIdx.x;       // 0..127
    const float* wb = (j < NCLASS) ? W2 : Wres;
    int jj = j & (NCLASS - 1);
    const float* w1row = W1 + (size_t)k * NHID;
    float acc = 0.f;
    for (int m = 0; m < NHID; ++m)
        acc += w1row[m] * wb[(size_t)m * NCLASS + jj];
    WT[(size_t)j * NFEAT + k] = f2bf(acc);
}

// c2[j] = b1 @ W2 ; cr[j] = b1 @ Wres + bres
__global__ void k_prep_c(const float* __restrict__ b1, const float* __restrict__ W2,
                         const float* __restrict__ Wres, const float* __restrict__ bres,
                         float* __restrict__ c2, float* __restrict__ cr) {
    int j = threadIdx.x;  // 0..127
    const float* wb = (j < NCLASS) ? W2 : Wres;
    int jj = j & (NCLASS - 1);
    float acc = 0.f;
    for (int m = 0; m < NHID; ++m)
        acc += b1[m] * wb[(size_t)m * NCLASS + jj];
    if (j < NCLASS) c2[jj] = acc;
    else            cr[jj] = acc + bres[jj];
}

// ---------------------------------------------------------------------------
// MFMA GEMM: A_bf16[N,128] = bf16(X[N,512] @ Wcat[512,128])
// ---------------------------------------------------------------------------
#define GBM 128
#define GBK 32
__global__ __launch_bounds__(256) void k_gemm_a(const float* __restrict__ X,
                                                const unsigned short* __restrict__ WT,
                                                unsigned short* __restrict__ A) {
    __shared__ __align__(16) short As[GBM * GBK];  // 8 KB
    __shared__ __align__(16) short Bs[FCAT * GBK]; // 8 KB
    int tid = threadIdx.x;
    int lane = tid & 63;
    int w = tid >> 6;
    int row0 = blockIdx.x * GBM;
    f32x4 acc[2][8] = {};

    for (int k0 = 0; k0 < NFEAT; k0 += GBK) {
#pragma unroll
        for (int q = 0; q < 4; ++q) {
            int s = tid + q * 256;
            int r = s >> 3, c = s & 7;
            int gr = row0 + r;
            float4 v = make_float4(0.f, 0.f, 0.f, 0.f);
            if (gr < N_NODES)
                v = *(const float4*)(X + (size_t)gr * NFEAT + k0 + c * 4);
            int c8 = c >> 1;
            int c8s = c8 ^ ((r >> 1) & 3);
            ushort4 pv = make_ushort4(f2bf(v.x), f2bf(v.y), f2bf(v.z), f2bf(v.w));
            *(ushort4*)((unsigned short*)As + r * GBK + c8s * 8 + (c & 1) * 4) = pv;
        }
#pragma unroll
        for (int q = 0; q < 2; ++q) {
            int s = tid + q * 256;
            int n = s >> 2, c8 = s & 3;
            int c8s = c8 ^ ((n >> 1) & 3);
            *(uint4*)((unsigned short*)Bs + n * GBK + c8s * 8) =
                *(const uint4*)(WT + (size_t)n * NFEAT + k0 + c8 * 8);
        }
        __syncthreads();

        int lr = lane & 15, ls = lane >> 4;
        short8 af[2];
#pragma unroll
        for (int mf = 0; mf < 2; ++mf) {
            int r = w * 32 + mf * 16 + lr;
            int ss = ls ^ ((r >> 1) & 3);
            af[mf] = *(short8*)(As + r * GBK + ss * 8);
        }
#pragma unroll
        for (int nf = 0; nf < 8; ++nf) {
            int n = nf * 16 + lr;
            int ss = ls ^ ((n >> 1) & 3);
            short8 bfr = *(short8*)(Bs + n * GBK + ss * 8);
            acc[0][nf] = __builtin_amdgcn_mfma_f32_16x16x32_bf16(af[0], bfr, acc[0][nf], 0, 0, 0);
            acc[1][nf] = __builtin_amdgcn_mfma_f32_16x16x32_bf16(af[1], bfr, acc[1][nf], 0, 0, 0);
        }
        __syncthreads();
    }

    int lr = lane & 15, lq = lane >> 4;
#pragma unroll
    for (int mf = 0; mf < 2; ++mf) {
#pragma unroll
        for (int j = 0; j < 4; ++j) {
            int gr = row0 + w * 32 + mf * 16 + lq * 4 + j;
            if (gr < N_NODES) {
#pragma unroll
                for (int nf = 0; nf < 8; ++nf)
                    A[(size_t)gr * FCAT + nf * 16 + lr] = f2bf(acc[mf][nf][j]);
            }
        }
    }
}

// ---------------------------------------------------------------------------
// CSR build — two-phase bucketed scatter (bucket = row >> 7)
// ---------------------------------------------------------------------------
__global__ void k_hist(const int* __restrict__ rows, int* __restrict__ deg) {
    int e = blockIdx.x * 256 + threadIdx.x;
    if (e < N_EDGES) atomicAdd(&deg[rows[e]], 1);
}

__global__ void k_blocksums(const int* __restrict__ deg, int* __restrict__ blksum) {
    __shared__ int sh[256];
    int i = blockIdx.x * 256 + threadIdx.x;
    sh[threadIdx.x] = (i < N_NODES) ? deg[i] : 0;
    __syncthreads();
    for (int off = 128; off > 0; off >>= 1) {
        if (threadIdx.x < off) sh[threadIdx.x] += sh[threadIdx.x + off];
        __syncthreads();
    }
    if (threadIdx.x == 0) blksum[blockIdx.x] = sh[0];
}

__global__ void k_scan_blk(const int* __restrict__ blksum, int* __restrict__ blkofs,
                           int nblk, int* __restrict__ row_ofs) {
    if (threadIdx.x == 0 && blockIdx.x == 0) {
        int sum = 0;
        for (int b = 0; b < nblk; ++b) { blkofs[b] = sum; sum += blksum[b]; }
        row_ofs[N_NODES] = sum;
    }
}

// writes row_ofs and seeds per-bucket cursors (= row_ofs at bucket base)
__global__ void k_scan_local(const int* __restrict__ deg, const int* __restrict__ blkofs,
                             int* __restrict__ row_ofs, int* __restrict__ bcursor) {
    __shared__ int sh[256];
    int i = blockIdx.x * 256 + threadIdx.x;
    int v = (i < N_NODES) ? deg[i] : 0;
    sh[threadIdx.x] = v;
    __syncthreads();
    for (int off = 1; off < 256; off <<= 1) {
        int t = (threadIdx.x >= off) ? sh[threadIdx.x - off] : 0;
        __syncthreads();
        sh[threadIdx.x] += t;
        __syncthreads();
    }
    if (i < N_NODES) {
        int ex = blkofs[blockIdx.x] + sh[threadIdx.x] - v;  // exclusive
        row_ofs[i] = ex;
        if ((i & 127) == 0) bcursor[i >> 7] = ex;
    }
}

// pass 1: edges -> bucket regions, packed {row_local<<17 | col, val}
__global__ void k_bucket(const int* __restrict__ rows, const int* __restrict__ cols,
                         const float* __restrict__ vals, int* __restrict__ bcursor,
                         int2* __restrict__ stage) {
    int e = blockIdx.x * 256 + threadIdx.x;
    if (e < N_EDGES) {
        int r = rows[e];
        int p = atomicAdd(&bcursor[r >> 7], 1);
        stage[p] = make_int2(((r & 127) << 17) | cols[e], __float_as_int(vals[e]));
    }
}

// pass 2: bucket -> final CSR slots via LDS row cursors (all traffic L2-local)
__global__ __launch_bounds__(256) void k_csr(const int2* __restrict__ stage,
                                             const int* __restrict__ row_ofs,
                                             int2* __restrict__ csr) {
    __shared__ int cur[128];
    int n0 = blockIdx.x << 7;
    int t = threadIdx.x;
    if (t < 128) {
        int idx = n0 + t;
        cur[t] = row_ofs[idx < N_NODES ? idx : N_NODES];
    }
    __syncthreads();
    int nend = n0 + 128; if (nend > N_NODES) nend = N_NODES;
    int s = row_ofs[n0], e = row_ofs[nend];
    for (int i = s + t; i < e; i += 256) {
        int2 ev = stage[i];
        int rl = ((unsigned)ev.x) >> 17;
        int p = atomicAdd(&cur[rl], 1);
        csr[p] = make_int2(ev.x & 0x1FFFF, ev.y);
    }
}

// ---------------------------------------------------------------------------
// SpMM 1: gathers bf16 A rows (256 B/edge). Lane l owns cols {2l, 2l+1}.
// ---------------------------------------------------------------------------
__global__ __launch_bounds__(256) void k_spmm1(const unsigned* __restrict__ A32,
                                               const int* __restrict__ row_ofs,
                                               const int2* __restrict__ csr,
                                               unsigned* __restrict__ S1a,
                                               float2* __restrict__ S1r) {
    int wv = threadIdx.x >> 6, lane = threadIdx.x & 63;
    int node = blockIdx.x * 4 + wv;
    if (node >= N_NODES) return;
    int s = row_ofs[node], e = row_ofs[node + 1];
    float a0 = 0.f, a1 = 0.f;
    int t = s;
    for (; t + 1 < e; t += 2) {
        int2 cv0 = csr[t], cv1 = csr[t + 1];
        unsigned p0 = A32[cv0.x * 64 + lane];
        unsigned p1 = A32[cv1.x * 64 + lane];
        float v0 = __int_as_float(cv0.y), v1 = __int_as_float(cv1.y);
        a0 += v0 * bf2f(p0 & 0xffffu) + v1 * bf2f(p1 & 0xffffu);
        a1 += v0 * bf2f(p0 >> 16) + v1 * bf2f(p1 >> 16);
    }
    if (t < e) {
        int2 cv = csr[t];
        unsigned p = A32[cv.x * 64 + lane];
        float v = __int_as_float(cv.y);
        a0 += v * bf2f(p & 0xffffu);
        a1 += v * bf2f(p >> 16);
    }
    if (lane < 32)
        S1a[node * 32 + lane] = (unsigned)f2bf(a0) | ((unsigned)f2bf(a1) << 16);
    else
        S1r[node * 32 + (lane - 32)] = make_float2(a0, a1);
}

// ---------------------------------------------------------------------------
// SpMM 2 + fused epilogue (gathers bf16 S1a rows, 128 B/edge)
// ---------------------------------------------------------------------------
__global__ __launch_bounds__(256) void k_spmm2_out(const unsigned short* __restrict__ S1a16,
                                                   const float* __restrict__ S1r,
                                                   const int* __restrict__ row_ofs,
                                                   const int2* __restrict__ csr,
                                                   const float* __restrict__ c2,
                                                   const float* __restrict__ cr,
                                                   const float* __restrict__ b2,
                                                   float* __restrict__ out) {
    int wv = threadIdx.x >> 6, lane = threadIdx.x & 63;
    int node = blockIdx.x * 4 + wv;
    if (node >= N_NODES) return;
    int s = row_ofs[node], e = row_ofs[node + 1];
    float acc = 0.f, rsum = 0.f;
    int t = s;
    for (; t + 1 < e; t += 2) {
        int2 cv0 = csr[t], cv1 = csr[t + 1];
        float v0 = __int_as_float(cv0.y), v1 = __int_as_float(cv1.y);
        rsum += v0 + v1;
        acc += v0 * bf2f((unsigned)S1a16[cv0.x * 64 + lane])
             + v1 * bf2f((unsigned)S1a16[cv1.x * 64 + lane]);
    }
    if (t < e) {
        int2 cv = csr[t];
        float v = __int_as_float(cv.y);
        rsum += v;
        acc += v * bf2f((unsigned)S1a16[cv.x * 64 + lane]);
    }
    float o = acc + rsum * c2[lane] + b2[lane];
    float res = S1r[node * 64 + lane] + cr[lane];
    out[node * 64 + lane] = fmaxf(o, 0.f) + res;
}

// ---------------------------------------------------------------------------
extern "C" void kernel_launch(void* const* d_in, const int* in_sizes, int n_in,
                              void* d_out, int out_size, void* d_ws, size_t ws_size,
                              hipStream_t stream) {
    const float* x        = (const float*)d_in[0];
    const int*   adj_rows = (const int*)d_in[1];
    const int*   adj_cols = (const int*)d_in[2];
    const float* adj_vals = (const float*)d_in[3];
    const float* W1       = (const float*)d_in[4];
    const float* b1       = (const float*)d_in[5];
    const float* W2       = (const float*)d_in[6];
    const float* b2       = (const float*)d_in[7];
    const float* Wres     = (const float*)d_in[8];
    const float* bres     = (const float*)d_in[9];
    float* out = (float*)d_out;

    char* ws = (char*)d_ws;
    size_t off = 0;
    auto alloc = [&](size_t bytes) {
        size_t o = off;
        off += (bytes + 511) & ~511ULL;
        return o;
    };
    const int NBLK_SCAN = (N_NODES + 255) / 256;  // 391

    unsigned short* WT  = (unsigned short*)(ws + alloc((size_t)NFEAT * FCAT * 2));
    float* c2           = (float*)(ws + alloc(NCLASS * 4));
    float* cr           = (float*)(ws + alloc(NCLASS * 4));
    // stage (CSR build) and A (GEMM/spmm1) time-share one 25.6 MB buffer:
    // stage dies at k_csr, A is written by k_gemm_a afterwards.
    char* unionbuf      = ws + alloc((size_t)N_EDGES * 8);  // >= N_NODES*FCAT*2
    int2* stage         = (int2*)unionbuf;
    unsigned short* A   = (unsigned short*)unionbuf;
    unsigned* S1a       = (unsigned*)(ws + alloc((size_t)N_NODES * 32 * 4));
    float* S1r          = (float*)(ws + alloc((size_t)N_NODES * 64 * 4));
    int*   deg      = (int*)(ws + alloc((size_t)N_NODES * 4));
    int*   row_ofs  = (int*)(ws + alloc((size_t)(N_NODES + 1) * 4));
    int*   bcursor  = (int*)(ws + alloc((size_t)NB * 4));
    int*   blksum   = (int*)(ws + alloc((size_t)NBLK_SCAN * 4));
    int*   blkofs   = (int*)(ws + alloc((size_t)NBLK_SCAN * 4));
    int2*  csr      = (int2*)(ws + alloc((size_t)N_EDGES * 8));
    (void)ws_size; (void)in_sizes; (void)n_in; (void)out_size;

    // weight prep (tiny)
    k_prep_wcat<<<NFEAT, FCAT, 0, stream>>>(W1, W2, Wres, WT);
    k_prep_c<<<1, FCAT, 0, stream>>>(b1, W2, Wres, bres, c2, cr);

    // CSR build (before GEMM so stage can alias A)
    hipMemsetAsync(deg, 0, (size_t)N_NODES * 4, stream);
    k_hist<<<(N_EDGES + 255) / 256, 256, 0, stream>>>(adj_rows, deg);
    k_blocksums<<<NBLK_SCAN, 256, 0, stream>>>(deg, blksum);
    k_scan_blk<<<1, 64, 0, stream>>>(blksum, blkofs, NBLK_SCAN, row_ofs);
    k_scan_local<<<NBLK_SCAN, 256, 0, stream>>>(deg, blkofs, row_ofs, bcursor);
    k_bucket<<<(N_EDGES + 255) / 256, 256, 0, stream>>>(adj_rows, adj_cols, adj_vals,
                                                        bcursor, stage);
    k_csr<<<NB, 256, 0, stream>>>(stage, row_ofs, csr);

    // dense MFMA GEMM: A = bf16(x @ Wcat)   (overwrites stage)
    k_gemm_a<<<(N_NODES + GBM - 1) / GBM, 256, 0, stream>>>(x, WT, A);

    // spmm 1: S1 = spmm(A)  (bf16 gather)
    k_spmm1<<<(N_NODES + 3) / 4, 256, 0, stream>>>((const unsigned*)A, row_ofs, csr,
                                                   S1a, (float2*)S1r);

    // spmm 2 + epilogue
    k_spmm2_out<<<(N_NODES + 3) / 4, 256, 0, stream>>>((const unsigned short*)S1a, S1r,
                                                       row_ofs, csr, c2, cr, b2, out);
}

// Round 4
// 600.649 us; speedup vs baseline: 2.3250x; 2.3250x over previous
//
#include <hip/hip_runtime.h>

#define N_NODES 100000
#define N_EDGES 3200000
#define NFEAT 512
#define NHID 256
#define NCLASS 64
#define FCAT 128   // 2*NCLASS

#define RPB 64                         // rows per bucket
#define NB 1563                        // ceil(N_NODES / RPB)
#define CHUNK 8192                     // edges per partition block
#define NCH 391                        // ceil(N_EDGES / CHUNK)

typedef __attribute__((ext_vector_type(8))) short short8;
typedef __attribute__((ext_vector_type(4))) float f32x4;

static __device__ __forceinline__ unsigned short f2bf(float f) {
    unsigned u = __float_as_uint(f);
    unsigned r = (u + 0x7FFF + ((u >> 16) & 1)) >> 16;  // RNE
    return (unsigned short)r;
}
static __device__ __forceinline__ float bf2f(unsigned s) {
    return __uint_as_float(s << 16);
}

// ---------------------------------------------------------------------------
// Weight prep
// ---------------------------------------------------------------------------
__global__ void k_prep_wcat(const float* __restrict__ W1, const float* __restrict__ W2,
                            const float* __restrict__ Wres, unsigned short* __restrict__ WT) {
    int k = blockIdx.x;        // 0..511
    int j = threadIdx.x;       // 0..127
    const float* wb = (j < NCLASS) ? W2 : Wres;
    int jj = j & (NCLASS - 1);
    const float* w1row = W1 + (size_t)k * NHID;
    float acc = 0.f;
    for (int m = 0; m < NHID; ++m)
        acc += w1row[m] * wb[(size_t)m * NCLASS + jj];
    WT[(size_t)j * NFEAT + k] = f2bf(acc);
}

__global__ void k_prep_c(const float* __restrict__ b1, const float* __restrict__ W2,
                         const float* __restrict__ Wres, const float* __restrict__ bres,
                         float* __restrict__ c2, float* __restrict__ cr) {
    int j = threadIdx.x;  // 0..127
    const float* wb = (j < NCLASS) ? W2 : Wres;
    int jj = j & (NCLASS - 1);
    float acc = 0.f;
    for (int m = 0; m < NHID; ++m)
        acc += b1[m] * wb[(size_t)m * NCLASS + jj];
    if (j < NCLASS) c2[jj] = acc;
    else            cr[jj] = acc + bres[jj];
}

// ---------------------------------------------------------------------------
// MFMA GEMM: A_bf16[N,128] = bf16(X[N,512] @ Wcat[512,128])
// ---------------------------------------------------------------------------
#define GBM 128
#define GBK 32
__global__ __launch_bounds__(256) void k_gemm_a(const float* __restrict__ X,
                                                const unsigned short* __restrict__ WT,
                                                unsigned short* __restrict__ A) {
    __shared__ __align__(16) short As[GBM * GBK];  // 8 KB
    __shared__ __align__(16) short Bs[FCAT * GBK]; // 8 KB
    int tid = threadIdx.x;
    int lane = tid & 63;
    int w = tid >> 6;
    int row0 = blockIdx.x * GBM;
    f32x4 acc[2][8] = {};

    for (int k0 = 0; k0 < NFEAT; k0 += GBK) {
#pragma unroll
        for (int q = 0; q < 4; ++q) {
            int s = tid + q * 256;
            int r = s >> 3, c = s & 7;
            int gr = row0 + r;
            float4 v = make_float4(0.f, 0.f, 0.f, 0.f);
            if (gr < N_NODES)
                v = *(const float4*)(X + (size_t)gr * NFEAT + k0 + c * 4);
            int c8 = c >> 1;
            int c8s = c8 ^ ((r >> 1) & 3);
            ushort4 pv = make_ushort4(f2bf(v.x), f2bf(v.y), f2bf(v.z), f2bf(v.w));
            *(ushort4*)((unsigned short*)As + r * GBK + c8s * 8 + (c & 1) * 4) = pv;
        }
#pragma unroll
        for (int q = 0; q < 2; ++q) {
            int s = tid + q * 256;
            int n = s >> 2, c8 = s & 3;
            int c8s = c8 ^ ((n >> 1) & 3);
            *(uint4*)((unsigned short*)Bs + n * GBK + c8s * 8) =
                *(const uint4*)(WT + (size_t)n * NFEAT + k0 + c8 * 8);
        }
        __syncthreads();

        int lr = lane & 15, ls = lane >> 4;
        short8 af[2];
#pragma unroll
        for (int mf = 0; mf < 2; ++mf) {
            int r = w * 32 + mf * 16 + lr;
            int ss = ls ^ ((r >> 1) & 3);
            af[mf] = *(short8*)(As + r * GBK + ss * 8);
        }
#pragma unroll
        for (int nf = 0; nf < 8; ++nf) {
            int n = nf * 16 + lr;
            int ss = ls ^ ((n >> 1) & 3);
            short8 bfr = *(short8*)(Bs + n * GBK + ss * 8);
            acc[0][nf] = __builtin_amdgcn_mfma_f32_16x16x32_bf16(af[0], bfr, acc[0][nf], 0, 0, 0);
            acc[1][nf] = __builtin_amdgcn_mfma_f32_16x16x32_bf16(af[1], bfr, acc[1][nf], 0, 0, 0);
        }
        __syncthreads();
    }

    int lr = lane & 15, lq = lane >> 4;
#pragma unroll
    for (int mf = 0; mf < 2; ++mf) {
#pragma unroll
        for (int j = 0; j < 4; ++j) {
            int gr = row0 + w * 32 + mf * 16 + lq * 4 + j;
            if (gr < N_NODES) {
#pragma unroll
                for (int nf = 0; nf < 8; ++nf)
                    A[(size_t)gr * FCAT + nf * 16 + lr] = f2bf(acc[mf][nf][j]);
            }
        }
    }
}

// ---------------------------------------------------------------------------
// CSR build — atomic-free radix partition
// ---------------------------------------------------------------------------
// pass A: per-chunk bucket histogram (LDS atomics only)
__global__ __launch_bounds__(256) void k_hist_bkt(const int* __restrict__ rows,
                                                  int* __restrict__ HT) {
    __shared__ int h[NB];
    int c = blockIdx.x;
    for (int i = threadIdx.x; i < NB; i += 256) h[i] = 0;
    __syncthreads();
    int e0 = c * CHUNK;
    int eend = e0 + CHUNK; if (eend > N_EDGES) eend = N_EDGES;
    for (int e = e0 + threadIdx.x; e < eend; e += 256)
        atomicAdd(&h[rows[e] >> 6], 1);
    __syncthreads();
    for (int i = threadIdx.x; i < NB; i += 256)
        HT[(size_t)i * NCH + c] = h[i];  // [b][c], scattered fire-and-forget
}

// pass B1: per-bucket exclusive scan over chunks -> OFS[c][b]; totals -> T[b]
__global__ void k_scan_chunks(const int* __restrict__ HT, int* __restrict__ OFS,
                              int* __restrict__ T) {
    int b = blockIdx.x;
    int lane = threadIdx.x;  // 64
    const int* hb = HT + (size_t)b * NCH;
    int run = 0;
    for (int c0 = 0; c0 < NCH; c0 += 64) {
        int idx = c0 + lane;
        int v = (idx < NCH) ? hb[idx] : 0;
        int inc = v;
#pragma unroll
        for (int d = 1; d < 64; d <<= 1) {
            int t = __shfl_up(inc, d);
            if (lane >= d) inc += t;
        }
        if (idx < NCH) OFS[(size_t)idx * NB + b] = run + inc - v;  // exclusive
        run += __shfl(inc, 63);
    }
    if (lane == 0) T[b] = run;
}

// pass B2: scan bucket totals -> base[0..NB]; row_ofs[N] = E
__global__ void k_scan_base(const int* __restrict__ T, int* __restrict__ base,
                            int* __restrict__ row_ofs) {
    int lane = threadIdx.x;  // 64
    int run = 0;
    for (int c0 = 0; c0 < NB; c0 += 64) {
        int idx = c0 + lane;
        int v = (idx < NB) ? T[idx] : 0;
        int inc = v;
#pragma unroll
        for (int d = 1; d < 64; d <<= 1) {
            int t = __shfl_up(inc, d);
            if (lane >= d) inc += t;
        }
        if (idx < NB) base[idx] = run + inc - v;
        run += __shfl(inc, 63);
    }
    if (lane == 0) { base[NB] = run; row_ofs[N_NODES] = run; }
}

// pass C: scatter to bucket-staged order; slots via LDS cursors (no global atomics)
__global__ __launch_bounds__(256) void k_partition(const int* __restrict__ rows,
                                                   const int* __restrict__ cols,
                                                   const float* __restrict__ vals,
                                                   const int* __restrict__ OFS,
                                                   const int* __restrict__ base,
                                                   int2* __restrict__ stage) {
    __shared__ int cur[NB];
    int c = blockIdx.x;
    for (int i = threadIdx.x; i < NB; i += 256)
        cur[i] = base[i] + OFS[(size_t)c * NB + i];  // coalesced
    __syncthreads();
    int e0 = c * CHUNK;
    int eend = e0 + CHUNK; if (eend > N_EDGES) eend = N_EDGES;
    for (int e = e0 + threadIdx.x; e < eend; e += 256) {
        int r = rows[e];
        int p = atomicAdd(&cur[r >> 6], 1);  // LDS atomic, shallow chains
        stage[p] = make_int2(((r & 63) << 17) | cols[e], __float_as_int(vals[e]));
    }
}

// pass D: within-bucket row sort (L2-hot double read of 33 KB window),
// computes row_ofs from stage itself.
__global__ __launch_bounds__(256) void k_csr(const int2* __restrict__ stage,
                                             const int* __restrict__ base,
                                             int* __restrict__ row_ofs,
                                             int2* __restrict__ csr) {
    __shared__ int cnt[RPB];
    __shared__ int cur[RPB];
    int b = blockIdx.x, t = threadIdx.x;
    int s = base[b], e = base[b + 1];
    if (t < RPB) cnt[t] = 0;
    __syncthreads();
    for (int i = s + t; i < e; i += 256)
        atomicAdd(&cnt[((unsigned)stage[i].x) >> 17], 1);
    __syncthreads();
    if (t < 64) {  // wave 0: scan 64 counters
        int v = cnt[t];
        int inc = v;
#pragma unroll
        for (int d = 1; d < 64; d <<= 1) {
            int u = __shfl_up(inc, d);
            if (t >= d) inc += u;
        }
        int ex = s + inc - v;
        int n = b * RPB + t;
        if (n < N_NODES) row_ofs[n] = ex;
        cur[t] = ex;
    }
    __syncthreads();
    for (int i = s + t; i < e; i += 256) {
        int2 ev = stage[i];
        int rl = ((unsigned)ev.x) >> 17;
        int p = atomicAdd(&cur[rl], 1);
        csr[p] = make_int2(ev.x & 0x1FFFF, ev.y);
    }
}

// ---------------------------------------------------------------------------
// SpMM 1: gathers bf16 A rows (256 B/edge). Lane l owns cols {2l, 2l+1}.
// ---------------------------------------------------------------------------
__global__ __launch_bounds__(256) void k_spmm1(const unsigned* __restrict__ A32,
                                               const int* __restrict__ row_ofs,
                                               const int2* __restrict__ csr,
                                               unsigned* __restrict__ S1a,
                                               float2* __restrict__ S1r) {
    int wv = threadIdx.x >> 6, lane = threadIdx.x & 63;
    int node = blockIdx.x * 4 + wv;
    if (node >= N_NODES) return;
    int s = row_ofs[node], e = row_ofs[node + 1];
    float a0 = 0.f, a1 = 0.f;
    int t = s;
    for (; t + 1 < e; t += 2) {
        int2 cv0 = csr[t], cv1 = csr[t + 1];
        unsigned p0 = A32[cv0.x * 64 + lane];
        unsigned p1 = A32[cv1.x * 64 + lane];
        float v0 = __int_as_float(cv0.y), v1 = __int_as_float(cv1.y);
        a0 += v0 * bf2f(p0 & 0xffffu) + v1 * bf2f(p1 & 0xffffu);
        a1 += v0 * bf2f(p0 >> 16) + v1 * bf2f(p1 >> 16);
    }
    if (t < e) {
        int2 cv = csr[t];
        unsigned p = A32[cv.x * 64 + lane];
        float v = __int_as_float(cv.y);
        a0 += v * bf2f(p & 0xffffu);
        a1 += v * bf2f(p >> 16);
    }
    if (lane < 32)
        S1a[node * 32 + lane] = (unsigned)f2bf(a0) | ((unsigned)f2bf(a1) << 16);
    else
        S1r[node * 32 + (lane - 32)] = make_float2(a0, a1);
}

// ---------------------------------------------------------------------------
// SpMM 2 + fused epilogue (gathers bf16 S1a rows, 128 B/edge)
// ---------------------------------------------------------------------------
__global__ __launch_bounds__(256) void k_spmm2_out(const unsigned short* __restrict__ S1a16,
                                                   const float* __restrict__ S1r,
                                                   const int* __restrict__ row_ofs,
                                                   const int2* __restrict__ csr,
                                                   const float* __restrict__ c2,
                                                   const float* __restrict__ cr,
                                                   const float* __restrict__ b2,
                                                   float* __restrict__ out) {
    int wv = threadIdx.x >> 6, lane = threadIdx.x & 63;
    int node = blockIdx.x * 4 + wv;
    if (node >= N_NODES) return;
    int s = row_ofs[node], e = row_ofs[node + 1];
    float acc = 0.f, rsum = 0.f;
    int t = s;
    for (; t + 1 < e; t += 2) {
        int2 cv0 = csr[t], cv1 = csr[t + 1];
        float v0 = __int_as_float(cv0.y), v1 = __int_as_float(cv1.y);
        rsum += v0 + v1;
        acc += v0 * bf2f((unsigned)S1a16[cv0.x * 64 + lane])
             + v1 * bf2f((unsigned)S1a16[cv1.x * 64 + lane]);
    }
    if (t < e) {
        int2 cv = csr[t];
        float v = __int_as_float(cv.y);
        rsum += v;
        acc += v * bf2f((unsigned)S1a16[cv.x * 64 + lane]);
    }
    float o = acc + rsum * c2[lane] + b2[lane];
    float res = S1r[node * 64 + lane] + cr[lane];
    out[node * 64 + lane] = fmaxf(o, 0.f) + res;
}

// ---------------------------------------------------------------------------
extern "C" void kernel_launch(void* const* d_in, const int* in_sizes, int n_in,
                              void* d_out, int out_size, void* d_ws, size_t ws_size,
                              hipStream_t stream) {
    const float* x        = (const float*)d_in[0];
    const int*   adj_rows = (const int*)d_in[1];
    const int*   adj_cols = (const int*)d_in[2];
    const float* adj_vals = (const float*)d_in[3];
    const float* W1       = (const float*)d_in[4];
    const float* b1       = (const float*)d_in[5];
    const float* W2       = (const float*)d_in[6];
    const float* b2       = (const float*)d_in[7];
    const float* Wres     = (const float*)d_in[8];
    const float* bres     = (const float*)d_in[9];
    float* out = (float*)d_out;

    char* ws = (char*)d_ws;
    size_t off = 0;
    auto alloc = [&](size_t bytes) {
        size_t o = off;
        off += (bytes + 511) & ~511ULL;
        return o;
    };

    unsigned short* WT  = (unsigned short*)(ws + alloc((size_t)NFEAT * FCAT * 2));
    float* c2           = (float*)(ws + alloc(NCLASS * 4));
    float* cr           = (float*)(ws + alloc(NCLASS * 4));
    // stage (CSR build) and A (GEMM/spmm1) time-share one 25.6 MB buffer
    char* unionbuf      = ws + alloc((size_t)N_EDGES * 8);
    int2* stage         = (int2*)unionbuf;
    unsigned short* A   = (unsigned short*)unionbuf;
    unsigned* S1a       = (unsigned*)(ws + alloc((size_t)N_NODES * 32 * 4));
    // S1r region time-shares with HT/OFS (dead after k_partition)
    char* s1r_region    = ws + alloc((size_t)N_NODES * 64 * 4);
    float* S1r          = (float*)s1r_region;
    int*   HT           = (int*)s1r_region;                               // NB*NCH ints = 2.44MB
    int*   OFS          = (int*)(s1r_region + ((size_t)NB * NCH * 4 + 511 & ~511ULL));
    int*   T            = (int*)(ws + alloc((size_t)NB * 4));
    int*   base         = (int*)(ws + alloc((size_t)(NB + 1) * 4));
    int*   row_ofs      = (int*)(ws + alloc((size_t)(N_NODES + 1) * 4));
    int2*  csr          = (int2*)(ws + alloc((size_t)N_EDGES * 8));
    (void)ws_size; (void)in_sizes; (void)n_in; (void)out_size;

    // weight prep (tiny)
    k_prep_wcat<<<NFEAT, FCAT, 0, stream>>>(W1, W2, Wres, WT);
    k_prep_c<<<1, FCAT, 0, stream>>>(b1, W2, Wres, bres, c2, cr);

    // CSR build: atomic-free partition + within-bucket sort
    k_hist_bkt<<<NCH, 256, 0, stream>>>(adj_rows, HT);
    k_scan_chunks<<<NB, 64, 0, stream>>>(HT, OFS, T);
    k_scan_base<<<1, 64, 0, stream>>>(T, base, row_ofs);
    k_partition<<<NCH, 256, 0, stream>>>(adj_rows, adj_cols, adj_vals, OFS, base, stage);
    k_csr<<<NB, 256, 0, stream>>>(stage, base, row_ofs, csr);

    // dense MFMA GEMM: A = bf16(x @ Wcat)   (overwrites stage)
    k_gemm_a<<<(N_NODES + GBM - 1) / GBM, 256, 0, stream>>>(x, WT, A);

    // spmm 1: S1 = spmm(A)  (bf16 gather; overwrites HT/OFS region with S1r)
    k_spmm1<<<(N_NODES + 3) / 4, 256, 0, stream>>>((const unsigned*)A, row_ofs, csr,
                                                   S1a, (float2*)S1r);

    // spmm 2 + epilogue
    k_spmm2_out<<<(N_NODES + 3) / 4, 256, 0, stream>>>((const unsigned short*)S1a, S1r,
                                                       row_ofs, csr, c2, cr, b2, out);
}

// Round 5
// 470.259 us; speedup vs baseline: 2.9697x; 1.2773x over previous
//
#include <hip/hip_runtime.h>

#define N_NODES 100000
#define N_EDGES 3200000
#define NFEAT 512
#define NHID 256
#define NCLASS 64
#define FCAT 128   // 2*NCLASS

#define RPB 64                         // rows per bucket
#define NB 1563                        // ceil(N_NODES / RPB)
#define CHUNK 8192                     // edges per partition block
#define NCH 391                        // ceil(N_EDGES / CHUNK)

typedef __attribute__((ext_vector_type(8))) short short8;
typedef __attribute__((ext_vector_type(4))) float f32x4;

static __device__ __forceinline__ unsigned short f2bf(float f) {
    unsigned u = __float_as_uint(f);
    unsigned r = (u + 0x7FFF + ((u >> 16) & 1)) >> 16;  // RNE
    return (unsigned short)r;
}
static __device__ __forceinline__ float bf2f(unsigned s) {
    return __uint_as_float(s << 16);
}

// ---------------------------------------------------------------------------
// Weight prep
// ---------------------------------------------------------------------------
__global__ void k_prep_wcat(const float* __restrict__ W1, const float* __restrict__ W2,
                            const float* __restrict__ Wres, unsigned short* __restrict__ WT) {
    int k = blockIdx.x;        // 0..511
    int j = threadIdx.x;       // 0..127
    const float* wb = (j < NCLASS) ? W2 : Wres;
    int jj = j & (NCLASS - 1);
    const float* w1row = W1 + (size_t)k * NHID;
    float acc = 0.f;
    for (int m = 0; m < NHID; ++m)
        acc += w1row[m] * wb[(size_t)m * NCLASS + jj];
    WT[(size_t)j * NFEAT + k] = f2bf(acc);
}

__global__ void k_prep_c(const float* __restrict__ b1, const float* __restrict__ W2,
                         const float* __restrict__ Wres, const float* __restrict__ bres,
                         float* __restrict__ c2, float* __restrict__ cr) {
    int j = threadIdx.x;  // 0..127
    const float* wb = (j < NCLASS) ? W2 : Wres;
    int jj = j & (NCLASS - 1);
    float acc = 0.f;
    for (int m = 0; m < NHID; ++m)
        acc += b1[m] * wb[(size_t)m * NCLASS + jj];
    if (j < NCLASS) c2[jj] = acc;
    else            cr[jj] = acc + bres[jj];
}

// ---------------------------------------------------------------------------
// MFMA GEMM: A_bf16[N,128] = bf16(X[N,512] @ Wcat[512,128])
// ---------------------------------------------------------------------------
#define GBM 128
#define GBK 32
__global__ __launch_bounds__(256) void k_gemm_a(const float* __restrict__ X,
                                                const unsigned short* __restrict__ WT,
                                                unsigned short* __restrict__ A) {
    __shared__ __align__(16) short As[GBM * GBK];  // 8 KB
    __shared__ __align__(16) short Bs[FCAT * GBK]; // 8 KB
    int tid = threadIdx.x;
    int lane = tid & 63;
    int w = tid >> 6;
    int row0 = blockIdx.x * GBM;
    f32x4 acc[2][8] = {};

    for (int k0 = 0; k0 < NFEAT; k0 += GBK) {
#pragma unroll
        for (int q = 0; q < 4; ++q) {
            int s = tid + q * 256;
            int r = s >> 3, c = s & 7;
            int gr = row0 + r;
            float4 v = make_float4(0.f, 0.f, 0.f, 0.f);
            if (gr < N_NODES)
                v = *(const float4*)(X + (size_t)gr * NFEAT + k0 + c * 4);
            int c8 = c >> 1;
            int c8s = c8 ^ ((r >> 1) & 3);
            ushort4 pv = make_ushort4(f2bf(v.x), f2bf(v.y), f2bf(v.z), f2bf(v.w));
            *(ushort4*)((unsigned short*)As + r * GBK + c8s * 8 + (c & 1) * 4) = pv;
        }
#pragma unroll
        for (int q = 0; q < 2; ++q) {
            int s = tid + q * 256;
            int n = s >> 2, c8 = s & 3;
            int c8s = c8 ^ ((n >> 1) & 3);
            *(uint4*)((unsigned short*)Bs + n * GBK + c8s * 8) =
                *(const uint4*)(WT + (size_t)n * NFEAT + k0 + c8 * 8);
        }
        __syncthreads();

        int lr = lane & 15, ls = lane >> 4;
        short8 af[2];
#pragma unroll
        for (int mf = 0; mf < 2; ++mf) {
            int r = w * 32 + mf * 16 + lr;
            int ss = ls ^ ((r >> 1) & 3);
            af[mf] = *(short8*)(As + r * GBK + ss * 8);
        }
#pragma unroll
        for (int nf = 0; nf < 8; ++nf) {
            int n = nf * 16 + lr;
            int ss = ls ^ ((n >> 1) & 3);
            short8 bfr = *(short8*)(Bs + n * GBK + ss * 8);
            acc[0][nf] = __builtin_amdgcn_mfma_f32_16x16x32_bf16(af[0], bfr, acc[0][nf], 0, 0, 0);
            acc[1][nf] = __builtin_amdgcn_mfma_f32_16x16x32_bf16(af[1], bfr, acc[1][nf], 0, 0, 0);
        }
        __syncthreads();
    }

    int lr = lane & 15, lq = lane >> 4;
#pragma unroll
    for (int mf = 0; mf < 2; ++mf) {
#pragma unroll
        for (int j = 0; j < 4; ++j) {
            int gr = row0 + w * 32 + mf * 16 + lq * 4 + j;
            if (gr < N_NODES) {
#pragma unroll
                for (int nf = 0; nf < 8; ++nf)
                    A[(size_t)gr * FCAT + nf * 16 + lr] = f2bf(acc[mf][nf][j]);
            }
        }
    }
}

// ---------------------------------------------------------------------------
// CSR build — atomic-free radix partition
// ---------------------------------------------------------------------------
__global__ __launch_bounds__(256) void k_hist_bkt(const int* __restrict__ rows,
                                                  int* __restrict__ HT) {
    __shared__ int h[NB];
    int c = blockIdx.x;
    for (int i = threadIdx.x; i < NB; i += 256) h[i] = 0;
    __syncthreads();
    int e0 = c * CHUNK;
    int eend = e0 + CHUNK; if (eend > N_EDGES) eend = N_EDGES;
    for (int e = e0 + threadIdx.x; e < eend; e += 256)
        atomicAdd(&h[rows[e] >> 6], 1);
    __syncthreads();
    for (int i = threadIdx.x; i < NB; i += 256)
        HT[(size_t)i * NCH + c] = h[i];
}

__global__ void k_scan_chunks(const int* __restrict__ HT, int* __restrict__ OFS,
                              int* __restrict__ T) {
    int b = blockIdx.x;
    int lane = threadIdx.x;  // 64
    const int* hb = HT + (size_t)b * NCH;
    int run = 0;
    for (int c0 = 0; c0 < NCH; c0 += 64) {
        int idx = c0 + lane;
        int v = (idx < NCH) ? hb[idx] : 0;
        int inc = v;
#pragma unroll
        for (int d = 1; d < 64; d <<= 1) {
            int t = __shfl_up(inc, d);
            if (lane >= d) inc += t;
        }
        if (idx < NCH) OFS[(size_t)idx * NB + b] = run + inc - v;
        run += __shfl(inc, 63);
    }
    if (lane == 0) T[b] = run;
}

__global__ void k_scan_base(const int* __restrict__ T, int* __restrict__ base,
                            int* __restrict__ row_ofs) {
    int lane = threadIdx.x;  // 64
    int run = 0;
    for (int c0 = 0; c0 < NB; c0 += 64) {
        int idx = c0 + lane;
        int v = (idx < NB) ? T[idx] : 0;
        int inc = v;
#pragma unroll
        for (int d = 1; d < 64; d <<= 1) {
            int t = __shfl_up(inc, d);
            if (lane >= d) inc += t;
        }
        if (idx < NB) base[idx] = run + inc - v;
        run += __shfl(inc, 63);
    }
    if (lane == 0) { base[NB] = run; row_ofs[N_NODES] = run; }
}

__global__ __launch_bounds__(256) void k_partition(const int* __restrict__ rows,
                                                   const int* __restrict__ cols,
                                                   const float* __restrict__ vals,
                                                   const int* __restrict__ OFS,
                                                   const int* __restrict__ base,
                                                   int2* __restrict__ stage) {
    __shared__ int cur[NB];
    int c = blockIdx.x;
    for (int i = threadIdx.x; i < NB; i += 256)
        cur[i] = base[i] + OFS[(size_t)c * NB + i];
    __syncthreads();
    int e0 = c * CHUNK;
    int eend = e0 + CHUNK; if (eend > N_EDGES) eend = N_EDGES;
    for (int e = e0 + threadIdx.x; e < eend; e += 256) {
        int r = rows[e];
        int p = atomicAdd(&cur[r >> 6], 1);
        stage[p] = make_int2(((r & 63) << 17) | cols[e], __float_as_int(vals[e]));
    }
}

__global__ __launch_bounds__(256) void k_csr(const int2* __restrict__ stage,
                                             const int* __restrict__ base,
                                             int* __restrict__ row_ofs,
                                             int2* __restrict__ csr) {
    __shared__ int cnt[RPB];
    __shared__ int cur[RPB];
    int b = blockIdx.x, t = threadIdx.x;
    int s = base[b], e = base[b + 1];
    if (t < RPB) cnt[t] = 0;
    __syncthreads();
    for (int i = s + t; i < e; i += 256)
        atomicAdd(&cnt[((unsigned)stage[i].x) >> 17], 1);
    __syncthreads();
    if (t < 64) {
        int v = cnt[t];
        int inc = v;
#pragma unroll
        for (int d = 1; d < 64; d <<= 1) {
            int u = __shfl_up(inc, d);
            if (t >= d) inc += u;
        }
        int ex = s + inc - v;
        int n = b * RPB + t;
        if (n < N_NODES) row_ofs[n] = ex;
        cur[t] = ex;
    }
    __syncthreads();
    for (int i = s + t; i < e; i += 256) {
        int2 ev = stage[i];
        int rl = ((unsigned)ev.x) >> 17;
        int p = atomicAdd(&cur[rl], 1);
        csr[p] = make_int2(ev.x & 0x1FFFF, ev.y);
    }
}

// ---------------------------------------------------------------------------
// SpMM 1: 8-deep pipelined gather of bf16 A rows (256 B/edge).
// ---------------------------------------------------------------------------
__global__ __launch_bounds__(256) void k_spmm1(const unsigned* __restrict__ A32,
                                               const int* __restrict__ row_ofs,
                                               const int2* __restrict__ csr,
                                               unsigned* __restrict__ S1a,
                                               float2* __restrict__ S1r) {
    int wv = threadIdx.x >> 6, lane = threadIdx.x & 63;
    int node = blockIdx.x * 4 + wv;
    if (node >= N_NODES) return;
    int s = row_ofs[node], e = row_ofs[node + 1];
    float a0 = 0.f, a1 = 0.f;
    int t = s;
    for (; t + 8 <= e; t += 8) {
        int2 cv[8];
#pragma unroll
        for (int u = 0; u < 8; ++u) cv[u] = csr[t + u];
        unsigned p[8];
#pragma unroll
        for (int u = 0; u < 8; ++u) p[u] = A32[cv[u].x * 64 + lane];
#pragma unroll
        for (int u = 0; u < 8; ++u) {
            float v = __int_as_float(cv[u].y);
            a0 += v * bf2f(p[u] & 0xffffu);
            a1 += v * bf2f(p[u] >> 16);
        }
    }
    for (; t < e; ++t) {
        int2 cv = csr[t];
        unsigned p = A32[cv.x * 64 + lane];
        float v = __int_as_float(cv.y);
        a0 += v * bf2f(p & 0xffffu);
        a1 += v * bf2f(p >> 16);
    }
    if (lane < 32)
        S1a[node * 32 + lane] = (unsigned)f2bf(a0) | ((unsigned)f2bf(a1) << 16);
    else
        S1r[node * 32 + (lane - 32)] = make_float2(a0, a1);
}

// ---------------------------------------------------------------------------
// SpMM 2 + fused epilogue: 8-deep pipelined gather of bf16 S1a rows (128 B/edge)
// ---------------------------------------------------------------------------
__global__ __launch_bounds__(256) void k_spmm2_out(const unsigned short* __restrict__ S1a16,
                                                   const float* __restrict__ S1r,
                                                   const int* __restrict__ row_ofs,
                                                   const int2* __restrict__ csr,
                                                   const float* __restrict__ c2,
                                                   const float* __restrict__ cr,
                                                   const float* __restrict__ b2,
                                                   float* __restrict__ out) {
    int wv = threadIdx.x >> 6, lane = threadIdx.x & 63;
    int node = blockIdx.x * 4 + wv;
    if (node >= N_NODES) return;
    int s = row_ofs[node], e = row_ofs[node + 1];
    float acc = 0.f, rsum = 0.f;
    int t = s;
    for (; t + 8 <= e; t += 8) {
        int2 cv[8];
#pragma unroll
        for (int u = 0; u < 8; ++u) cv[u] = csr[t + u];
        unsigned short p[8];
#pragma unroll
        for (int u = 0; u < 8; ++u) p[u] = S1a16[cv[u].x * 64 + lane];
#pragma unroll
        for (int u = 0; u < 8; ++u) {
            float v = __int_as_float(cv[u].y);
            rsum += v;
            acc += v * bf2f((unsigned)p[u]);
        }
    }
    for (; t < e; ++t) {
        int2 cv = csr[t];
        float v = __int_as_float(cv.y);
        rsum += v;
        acc += v * bf2f((unsigned)S1a16[cv.x * 64 + lane]);
    }
    float o = acc + rsum * c2[lane] + b2[lane];
    float res = S1r[node * 64 + lane] + cr[lane];
    out[node * 64 + lane] = fmaxf(o, 0.f) + res;
}

// ---------------------------------------------------------------------------
extern "C" void kernel_launch(void* const* d_in, const int* in_sizes, int n_in,
                              void* d_out, int out_size, void* d_ws, size_t ws_size,
                              hipStream_t stream) {
    const float* x        = (const float*)d_in[0];
    const int*   adj_rows = (const int*)d_in[1];
    const int*   adj_cols = (const int*)d_in[2];
    const float* adj_vals = (const float*)d_in[3];
    const float* W1       = (const float*)d_in[4];
    const float* b1       = (const float*)d_in[5];
    const float* W2       = (const float*)d_in[6];
    const float* b2       = (const float*)d_in[7];
    const float* Wres     = (const float*)d_in[8];
    const float* bres     = (const float*)d_in[9];
    float* out = (float*)d_out;

    char* ws = (char*)d_ws;
    size_t off = 0;
    auto alloc = [&](size_t bytes) {
        size_t o = off;
        off += (bytes + 511) & ~511ULL;
        return o;
    };

    unsigned short* WT  = (unsigned short*)(ws + alloc((size_t)NFEAT * FCAT * 2));
    float* c2           = (float*)(ws + alloc(NCLASS * 4));
    float* cr           = (float*)(ws + alloc(NCLASS * 4));
    // stage (CSR build) and A (GEMM/spmm1) time-share one 25.6 MB buffer
    char* unionbuf      = ws + alloc((size_t)N_EDGES * 8);
    int2* stage         = (int2*)unionbuf;
    unsigned short* A   = (unsigned short*)unionbuf;
    unsigned* S1a       = (unsigned*)(ws + alloc((size_t)N_NODES * 32 * 4));
    // S1r region time-shares with HT/OFS (dead after k_partition)
    char* s1r_region    = ws + alloc((size_t)N_NODES * 64 * 4);
    float* S1r          = (float*)s1r_region;
    int*   HT           = (int*)s1r_region;
    int*   OFS          = (int*)(s1r_region + ((size_t)NB * NCH * 4 + 511 & ~511ULL));
    int*   T            = (int*)(ws + alloc((size_t)NB * 4));
    int*   base         = (int*)(ws + alloc((size_t)(NB + 1) * 4));
    int*   row_ofs      = (int*)(ws + alloc((size_t)(N_NODES + 1) * 4));
    int2*  csr          = (int2*)(ws + alloc((size_t)N_EDGES * 8));
    (void)ws_size; (void)in_sizes; (void)n_in; (void)out_size;

    // weight prep (tiny)
    k_prep_wcat<<<NFEAT, FCAT, 0, stream>>>(W1, W2, Wres, WT);
    k_prep_c<<<1, FCAT, 0, stream>>>(b1, W2, Wres, bres, c2, cr);

    // CSR build: atomic-free partition + within-bucket sort
    k_hist_bkt<<<NCH, 256, 0, stream>>>(adj_rows, HT);
    k_scan_chunks<<<NB, 64, 0, stream>>>(HT, OFS, T);
    k_scan_base<<<1, 64, 0, stream>>>(T, base, row_ofs);
    k_partition<<<NCH, 256, 0, stream>>>(adj_rows, adj_cols, adj_vals, OFS, base, stage);
    k_csr<<<NB, 256, 0, stream>>>(stage, base, row_ofs, csr);

    // dense MFMA GEMM: A = bf16(x @ Wcat)   (overwrites stage)
    k_gemm_a<<<(N_NODES + GBM - 1) / GBM, 256, 0, stream>>>(x, WT, A);

    // spmm 1: S1 = spmm(A)  (bf16 gather; overwrites HT/OFS region with S1r)
    k_spmm1<<<(N_NODES + 3) / 4, 256, 0, stream>>>((const unsigned*)A, row_ofs, csr,
                                                   S1a, (float2*)S1r);

    // spmm 2 + epilogue
    k_spmm2_out<<<(N_NODES + 3) / 4, 256, 0, stream>>>((const unsigned short*)S1a, S1r,
                                                       row_ofs, csr, c2, cr, b2, out);
}